// Round 2
// baseline (2300.846 us; speedup 1.0000x reference)
//
#include <hip/hip_runtime.h>
#include <hip/hip_bf16.h>

typedef __hip_bfloat16 bf16;

#define NGRAPH 512
#define BN_EPS 1e-5f

__device__ __forceinline__ float b2f(bf16 x) { return __bfloat162float(x); }

// Read element i of a buffer that is either bf16 (isbf16=1) or fp32 (isbf16=0).
__device__ __forceinline__ float load_f(const void* p, int i, int isbf16) {
    if (isbf16) {
        unsigned short u = ((const unsigned short*)p)[i];
        return __uint_as_float(((unsigned int)u) << 16);   // exact bf16->fp32
    }
    return ((const float*)p)[i];
}

// ---------------- dtype detection ----------------
// If x is bf16, even-index ushorts are bf16(N(0,1)) samples: |v| <= ~6.
// If x is fp32, even-index ushorts are low mantissa halves: random exponent,
// ~46%/sample have |v|>1024 (or NaN/Inf). 64 samples decide with certainty.
__global__ void detect_dtype(const void* __restrict__ x, int* __restrict__ flag) {
    int lane = threadIdx.x & 63;
    unsigned short u = ((const unsigned short*)x)[2 * lane];
    float f = __uint_as_float(((unsigned int)u) << 16);
    int crazy = (!(fabsf(f) <= 1024.0f)) ? 1 : 0;   // true for NaN/Inf too
    unsigned long long m = __ballot(crazy);
    if (threadIdx.x == 0) *flag = (m == 0ULL) ? 1 : 0;   // 1 = bf16, 0 = fp32
}

// ---------------- generic convert to fp32 ----------------
__global__ void cvt(const void* __restrict__ in, float* __restrict__ out,
                    int n, const int* __restrict__ flag) {
    int i = blockIdx.x * blockDim.x + threadIdx.x;
    if (i < n) out[i] = load_f(in, i, *flag);
}

// ---------------- fold BN params: y = relu(t*S + T), t = agg + selfloop ----
__global__ void fold_bn(const void* b, const void* g, const void* be,
                        const void* m, const void* v,
                        float* __restrict__ S, float* __restrict__ T,
                        int F, const int* __restrict__ flag) {
    int f = blockIdx.x * blockDim.x + threadIdx.x;
    if (f >= F) return;
    int isbf = *flag;
    float bb = load_f(b, f, isbf), gg = load_f(g, f, isbf);
    float bee = load_f(be, f, isbf), mm = load_f(m, f, isbf);
    float vv = load_f(v, f, isbf);
    float s = gg * rsqrtf(vv + BN_EPS);
    S[f] = s;
    T[f] = (bb - mm) * s + bee;
}

// ---------------- degree / norm ----------------
__global__ void init_deg(float* deg, int n) {
    int i = blockIdx.x * blockDim.x + threadIdx.x;
    if (i < n) deg[i] = 1.0f;   // self-loop
}

__global__ void count_deg(const int* __restrict__ dst, float* deg, int e) {
    int i = blockIdx.x * blockDim.x + threadIdx.x;
    if (i < e) atomicAdd(&deg[dst[i]], 1.0f);
}

__global__ void finalize_dis(float* deg, int n) {
    int i = blockIdx.x * blockDim.x + threadIdx.x;
    if (i < n) deg[i] = rsqrtf(deg[i]);   // deg >= 1 always
}

// ---------------- node-feature GEMM: C[M x NOUT] = A[M x K] @ W[K x NOUT] ----
// A: fp32 (RAWA=false) or raw-flagged input (RAWA=true). W: fp32. C: bf16.
template <int K, int NOUT, bool RAWA>
__global__ __launch_bounds__(NOUT) void gemm_node(
    const void* __restrict__ A, const float* __restrict__ W,
    bf16* __restrict__ C, int M, const int* __restrict__ flag) {
    __shared__ __align__(16) float Alds[16][K];
    const int r0 = blockIdx.x * 16;
    const int tid = threadIdx.x;
    const int isbf = RAWA ? *flag : 0;
    for (int idx = tid; idx < 16 * K; idx += NOUT) {
        int r = idx / K, k = idx - r * K;
        int row = r0 + r;
        float val = 0.0f;
        if (row < M)
            val = RAWA ? load_f(A, row * K + k, isbf)
                       : ((const float*)A)[row * K + k];
        Alds[r][k] = val;
    }
    __syncthreads();
    float acc[16];
#pragma unroll
    for (int r = 0; r < 16; r++) acc[r] = 0.0f;
    const int col = tid;
    for (int k = 0; k < K; k += 4) {
        float w0 = W[(k + 0) * NOUT + col];
        float w1 = W[(k + 1) * NOUT + col];
        float w2 = W[(k + 2) * NOUT + col];
        float w3 = W[(k + 3) * NOUT + col];
#pragma unroll
        for (int r = 0; r < 16; r++) {
            float4 a = *(const float4*)&Alds[r][k];
            acc[r] += a.x * w0 + a.y * w1 + a.z * w2 + a.w * w3;
        }
    }
#pragma unroll
    for (int r = 0; r < 16; r++) {
        int row = r0 + r;
        if (row < M) C[(size_t)row * NOUT + col] = __float2bfloat16(acc[r]);
    }
}

// ---------------- edge aggregation (one wave per edge, fp32 atomics) -------
template <int F>
__global__ void edge_agg(const int* __restrict__ src, const int* __restrict__ dst,
                         const float* __restrict__ dis, const bf16* __restrict__ ht,
                         float* __restrict__ agg, int e) {
    int w = (int)(((size_t)blockIdx.x * blockDim.x + threadIdx.x) >> 6);
    int lane = threadIdx.x & 63;
    if (w >= e) return;
    int s = src[w], d = dst[w];
    float nw = dis[s] * dis[d];
    const bf16* hr = ht + (size_t)s * F;
    float* ar = agg + (size_t)d * F;
#pragma unroll
    for (int c = 0; c < F / 64; c++) {
        int f = lane + 64 * c;
        atomicAdd(&ar[f], nw * b2f(hr[f]));
    }
}

// ---------------- self-loop + folded BN + ReLU (agg fp32 -> fp32) ----------
template <int F>
__global__ void bn_relu_k(float* __restrict__ agg, const bf16* __restrict__ ht,
                          const float* __restrict__ dis,
                          const float* __restrict__ S, const float* __restrict__ T,
                          int n) {
    int i = blockIdx.x * blockDim.x + threadIdx.x;
    if (i >= n * F) return;
    int node = i / F;
    int f = i & (F - 1);
    float di = dis[node];
    float t = agg[i] + b2f(ht[i]) * di * di;
    agg[i] = fmaxf(t * S[f] + T[f], 0.0f);
}

// ---------------- graph pooling ----------------
__global__ void pool_k(const float* __restrict__ h, const int* __restrict__ batch,
                       float* __restrict__ psum, float* __restrict__ pmax,
                       int* __restrict__ pcnt, int n) {
    int w = (int)(((size_t)blockIdx.x * blockDim.x + threadIdx.x) >> 6);
    int lane = threadIdx.x & 63;
    if (w >= n) return;
    int g = batch[w];
    if (lane == 0) atomicAdd(&pcnt[g], 1);
    const float* hr = h + (size_t)w * 256;
#pragma unroll
    for (int c = 0; c < 4; c++) {
        int f = lane + 64 * c;
        float val = hr[f];
        atomicAdd(&psum[g * 256 + f], val);
        // val >= 0 post-ReLU: int compare of float bits is order-preserving
        atomicMax((int*)&pmax[g * 256 + f], __float_as_int(val));
    }
}

__global__ void build_z(const float* __restrict__ psum, const float* __restrict__ pmax,
                        const int* __restrict__ pcnt, float* __restrict__ z) {
    int i = blockIdx.x * blockDim.x + threadIdx.x;
    if (i >= NGRAPH * 256) return;
    int g = i >> 8, f = i & 255;
    float c = (float)max(pcnt[g], 1);
    z[g * 512 + f] = psum[i] / c;
    z[g * 512 + 256 + f] = pmax[i];   // pmax init 0 == "where counts>0 else 0"
}

// ---------------- MLP GEMM (block per row), flag-aware W/bias reads --------
template <int K, int NOUT, bool GELU>
__global__ void mlp_gemm(const float* __restrict__ A, const void* __restrict__ W,
                         const void* __restrict__ bias, float* __restrict__ C,
                         const int* __restrict__ flag) {
    __shared__ float a[K];
    int row = blockIdx.x;
    for (int idx = threadIdx.x; idx < K; idx += blockDim.x) a[idx] = A[row * K + idx];
    __syncthreads();
    int col = threadIdx.x;
    if (col < NOUT) {
        int isbf = *flag;
        float acc = load_f(bias, col, isbf);
        if (isbf) {
            const bf16* w = (const bf16*)W;
            for (int k = 0; k < K; k++) acc += a[k] * b2f(w[k * NOUT + col]);
        } else {
            const float* w = (const float*)W;
            for (int k = 0; k < K; k++) acc += a[k] * w[k * NOUT + col];
        }
        if (GELU) acc = 0.5f * acc * (1.0f + erff(acc * 0.70710678118654752f));
        C[row * NOUT + col] = acc;
    }
}

// ---------------- output write (dtype matches detected input dtype) --------
__global__ void write_out(const float* __restrict__ in, void* __restrict__ out,
                          int n, const int* __restrict__ flag) {
    int i = blockIdx.x * blockDim.x + threadIdx.x;
    if (i >= n) return;
    if (*flag) ((bf16*)out)[i] = __float2bfloat16(in[i]);
    else       ((float*)out)[i] = in[i];
}

extern "C" void kernel_launch(void* const* d_in, const int* in_sizes, int n_in,
                              void* d_out, int out_size, void* d_ws, size_t ws_size,
                              hipStream_t stream) {
    const void* x     = d_in[0];
    const int*  ei    = (const int*)d_in[1];
    const int*  batch = (const int*)d_in[2];
    const void *W1 = d_in[3],  *b1 = d_in[4],  *g1 = d_in[5],  *be1 = d_in[6],  *m1 = d_in[7],  *v1 = d_in[8];
    const void *W2 = d_in[9],  *b2 = d_in[10], *g2 = d_in[11], *be2 = d_in[12], *m2 = d_in[13], *v2 = d_in[14];
    const void *W3 = d_in[15], *b3 = d_in[16], *g3 = d_in[17], *be3 = d_in[18], *m3 = d_in[19], *v3 = d_in[20];
    const void *Wm1 = d_in[21], *bm1 = d_in[22];
    const void *Wm2 = d_in[23], *bm2 = d_in[24];
    const void *Wm3 = d_in[25], *bm3 = d_in[26];

    const int n = in_sizes[0] / 64;     // 50000
    const int E = in_sizes[1] / 2;      // 800000
    const int* src = ei;
    const int* dst = ei + E;

    // -------- workspace carving (256B aligned), total ~80 MB --------
    size_t off = 0;
    auto carve = [&](size_t bytes) {
        void* p = (char*)d_ws + off;
        off += (bytes + 255) & ~(size_t)255;
        return p;
    };
    int*   flag = (int*)carve(4);
    float* dis  = (float*)carve((size_t)n * 4);
    float* A    = (float*)carve((size_t)n * 256 * 4);   // fp32 agg / h (ping)
    bf16*  B    = (bf16*)carve((size_t)n * 256 * 2);    // bf16 h_t (pong)
    float* W1f  = (float*)carve((size_t)64 * 128 * 4);
    float* W2f  = (float*)carve((size_t)128 * 256 * 4);
    float* W3f  = (float*)carve((size_t)256 * 256 * 4);
    float* S1 = (float*)carve(128 * 4); float* T1 = (float*)carve(128 * 4);
    float* S2 = (float*)carve(256 * 4); float* T2 = (float*)carve(256 * 4);
    float* S3 = (float*)carve(256 * 4); float* T3 = (float*)carve(256 * 4);
    float* psum = (float*)carve((size_t)NGRAPH * 256 * 4);
    float* pmax = (float*)carve((size_t)NGRAPH * 256 * 4);
    int*   pcnt = (int*)carve((size_t)NGRAPH * 4);
    float* z    = (float*)carve((size_t)NGRAPH * 512 * 4);
    float* z1   = (float*)carve((size_t)NGRAPH * 256 * 4);
    float* z2   = (float*)carve((size_t)NGRAPH * 128 * 4);
    float* z3   = (float*)carve((size_t)NGRAPH * 8 * 4);
    (void)ws_size; (void)n_in;

    const int BT = 256;

    // -------- dtype detection + weight converts + BN folding --------
    detect_dtype<<<1, 64, 0, stream>>>(x, flag);
    cvt<<<(64 * 128 + BT - 1) / BT, BT, 0, stream>>>(W1, W1f, 64 * 128, flag);
    cvt<<<(128 * 256 + BT - 1) / BT, BT, 0, stream>>>(W2, W2f, 128 * 256, flag);
    cvt<<<(256 * 256 + BT - 1) / BT, BT, 0, stream>>>(W3, W3f, 256 * 256, flag);
    fold_bn<<<1, 128, 0, stream>>>(b1, g1, be1, m1, v1, S1, T1, 128, flag);
    fold_bn<<<1, 256, 0, stream>>>(b2, g2, be2, m2, v2, S2, T2, 256, flag);
    fold_bn<<<1, 256, 0, stream>>>(b3, g3, be3, m3, v3, S3, T3, 256, flag);

    // -------- degree / dis --------
    init_deg<<<(n + BT - 1) / BT, BT, 0, stream>>>(dis, n);
    count_deg<<<(E + BT - 1) / BT, BT, 0, stream>>>(dst, dis, E);
    finalize_dis<<<(n + BT - 1) / BT, BT, 0, stream>>>(dis, n);

    const int gemm_blocks = (n + 15) / 16;
    const int agg_blocks = (int)(((size_t)E * 64 + BT - 1) / BT);

    // -------- layer 1: x(64) -> 128 --------
    gemm_node<64, 128, true><<<gemm_blocks, 128, 0, stream>>>(x, W1f, B, n, flag);
    hipMemsetAsync(A, 0, (size_t)n * 128 * 4, stream);
    edge_agg<128><<<agg_blocks, BT, 0, stream>>>(src, dst, dis, B, A, E);
    bn_relu_k<128><<<(n * 128 + BT - 1) / BT, BT, 0, stream>>>(A, B, dis, S1, T1, n);

    // -------- layer 2: 128 -> 256 --------
    gemm_node<128, 256, false><<<gemm_blocks, 256, 0, stream>>>(A, W2f, B, n, flag);
    hipMemsetAsync(A, 0, (size_t)n * 256 * 4, stream);
    edge_agg<256><<<agg_blocks, BT, 0, stream>>>(src, dst, dis, B, A, E);
    bn_relu_k<256><<<(n * 256 + BT - 1) / BT, BT, 0, stream>>>(A, B, dis, S2, T2, n);

    // -------- layer 3: 256 -> 256 --------
    gemm_node<256, 256, false><<<gemm_blocks, 256, 0, stream>>>(A, W3f, B, n, flag);
    hipMemsetAsync(A, 0, (size_t)n * 256 * 4, stream);
    edge_agg<256><<<agg_blocks, BT, 0, stream>>>(src, dst, dis, B, A, E);
    bn_relu_k<256><<<(n * 256 + BT - 1) / BT, BT, 0, stream>>>(A, B, dis, S3, T3, n);

    // -------- pooling --------
    hipMemsetAsync(psum, 0, (size_t)NGRAPH * 256 * 4, stream);
    hipMemsetAsync(pmax, 0, (size_t)NGRAPH * 256 * 4, stream);
    hipMemsetAsync(pcnt, 0, (size_t)NGRAPH * 4, stream);
    pool_k<<<(int)(((size_t)n * 64 + BT - 1) / BT), BT, 0, stream>>>(A, batch, psum, pmax, pcnt, n);
    build_z<<<(NGRAPH * 256 + BT - 1) / BT, BT, 0, stream>>>(psum, pmax, pcnt, z);

    // -------- MLP head --------
    mlp_gemm<512, 256, true><<<NGRAPH, 256, 0, stream>>>(z, Wm1, bm1, z1, flag);
    mlp_gemm<256, 128, true><<<NGRAPH, 256, 0, stream>>>(z1, Wm2, bm2, z2, flag);
    mlp_gemm<128, 6, false><<<NGRAPH, 128, 0, stream>>>(z2, Wm3, bm3, z3, flag);
    write_out<<<(NGRAPH * 6 + BT - 1) / BT, BT, 0, stream>>>(z3, d_out, NGRAPH * 6, flag);
}

// Round 3
// 851.394 us; speedup vs baseline: 2.7024x; 2.7024x over previous
//
#include <hip/hip_runtime.h>
#include <hip/hip_bf16.h>

typedef __hip_bfloat16 bf16;

#define NGRAPH 512
#define BN_EPS 1e-5f

__device__ __forceinline__ float b2f(bf16 x) { return __bfloat162float(x); }
__device__ __forceinline__ float bf_lo(unsigned u) { return __uint_as_float(u << 16); }
__device__ __forceinline__ float bf_hi(unsigned u) { return __uint_as_float(u & 0xffff0000u); }

// Read element i of a buffer that is either bf16 (isbf16=1) or fp32 (isbf16=0).
__device__ __forceinline__ float load_f(const void* p, int i, int isbf16) {
    if (isbf16) {
        unsigned short u = ((const unsigned short*)p)[i];
        return __uint_as_float(((unsigned int)u) << 16);
    }
    return ((const float*)p)[i];
}

// ---------------- dtype detection (robustness; measured fp32 on this rig) --
__global__ void detect_dtype(const void* __restrict__ x, int* __restrict__ flag) {
    int lane = threadIdx.x & 63;
    unsigned short u = ((const unsigned short*)x)[2 * lane];
    float f = __uint_as_float(((unsigned int)u) << 16);
    int crazy = (!(fabsf(f) <= 1024.0f)) ? 1 : 0;
    unsigned long long m = __ballot(crazy);
    if (threadIdx.x == 0) *flag = (m == 0ULL) ? 1 : 0;   // 1 = bf16, 0 = fp32
}

__global__ void cvt(const void* __restrict__ in, float* __restrict__ out,
                    int n, const int* __restrict__ flag) {
    int i = blockIdx.x * blockDim.x + threadIdx.x;
    if (i < n) out[i] = load_f(in, i, *flag);
}

__global__ void fold_bn(const void* b, const void* g, const void* be,
                        const void* m, const void* v,
                        float* __restrict__ S, float* __restrict__ T,
                        int F, const int* __restrict__ flag) {
    int f = blockIdx.x * blockDim.x + threadIdx.x;
    if (f >= F) return;
    int isbf = *flag;
    float bb = load_f(b, f, isbf), gg = load_f(g, f, isbf);
    float bee = load_f(be, f, isbf), mm = load_f(m, f, isbf);
    float vv = load_f(v, f, isbf);
    float s = gg * rsqrtf(vv + BN_EPS);
    S[f] = s;
    T[f] = (bb - mm) * s + bee;
}

// ---------------- CSR build (once; reused by all 3 layers) ----------------
__global__ void count_deg_i(const int* __restrict__ dst, int* __restrict__ deg, int e) {
    int i = blockIdx.x * blockDim.x + threadIdx.x;
    if (i < e) atomicAdd(&deg[dst[i]], 1);
}

// Reserve a CSR segment per node (order irrelevant -> no prefix scan needed).
__global__ void reserve_rows(const int* __restrict__ deg, int* __restrict__ row_start,
                             int* __restrict__ cursor, float* __restrict__ dis,
                             int* __restrict__ total, int n) {
    int i = blockIdx.x * blockDim.x + threadIdx.x;
    if (i >= n) return;
    int d = deg[i];
    int s = atomicAdd(total, d);
    row_start[i] = s;
    cursor[i] = s;
    dis[i] = rsqrtf((float)(d + 1));   // +1 self-loop
}

__global__ void scatter_edges(const int* __restrict__ src, const int* __restrict__ dst,
                              int* __restrict__ cursor, int* __restrict__ csr_src, int e) {
    int i = blockIdx.x * blockDim.x + threadIdx.x;
    if (i >= e) return;
    int pos = atomicAdd(&cursor[dst[i]], 1);
    csr_src[pos] = src[i];
}

// ---------------- node-feature GEMM: C[M x NOUT] = A[M x K] @ W[K x NOUT] ----
template <int K, int NOUT, bool RAWA>
__global__ __launch_bounds__(NOUT) void gemm_node(
    const void* __restrict__ A, const float* __restrict__ W,
    bf16* __restrict__ C, int M, const int* __restrict__ flag) {
    __shared__ __align__(16) float Alds[16][K];
    const int r0 = blockIdx.x * 16;
    const int tid = threadIdx.x;
    const int isbf = RAWA ? *flag : 0;
    for (int idx = tid; idx < 16 * K; idx += NOUT) {
        int r = idx / K, k = idx - r * K;
        int row = r0 + r;
        float val = 0.0f;
        if (row < M)
            val = RAWA ? load_f(A, row * K + k, isbf)
                       : ((const float*)A)[row * K + k];
        Alds[r][k] = val;
    }
    __syncthreads();
    float acc[16];
#pragma unroll
    for (int r = 0; r < 16; r++) acc[r] = 0.0f;
    const int col = tid;
    for (int k = 0; k < K; k += 4) {
        float w0 = W[(k + 0) * NOUT + col];
        float w1 = W[(k + 1) * NOUT + col];
        float w2 = W[(k + 2) * NOUT + col];
        float w3 = W[(k + 3) * NOUT + col];
#pragma unroll
        for (int r = 0; r < 16; r++) {
            float4 a = *(const float4*)&Alds[r][k];
            acc[r] += a.x * w0 + a.y * w1 + a.z * w2 + a.w * w3;
        }
    }
#pragma unroll
    for (int r = 0; r < 16; r++) {
        int row = r0 + r;
        if (row < M) C[(size_t)row * NOUT + col] = __float2bfloat16(acc[r]);
    }
}

// ---------------- CSR aggregation, fused self-loop + BN + ReLU -------------
// One wave per destination node. VPL = features per lane (F = 64*VPL).
template <int VPL>
__global__ __launch_bounds__(256) void csr_agg(
    const int* __restrict__ row_start, const int* __restrict__ deg,
    const float* __restrict__ dis, const int* __restrict__ csr_src,
    const bf16* __restrict__ ht,
    const float* __restrict__ S, const float* __restrict__ T,
    float* __restrict__ out, int n) {
    const int F = VPL * 64;
    int wid = (int)(((size_t)blockIdx.x * blockDim.x + threadIdx.x) >> 6);
    int lane = threadIdx.x & 63;
    if (wid >= n) return;
    int start = row_start[wid];
    int d = deg[wid];
    float disd = dis[wid];
    float dd = disd * disd;

    float acc[VPL];
    // self-loop init
    {
        const bf16* self = ht + (size_t)wid * F + lane * VPL;
        if (VPL == 4) {
            uint2 u = *(const uint2*)self;
            acc[0] = bf_lo(u.x) * dd; acc[1] = bf_hi(u.x) * dd;
            acc[2] = bf_lo(u.y) * dd; acc[3] = bf_hi(u.y) * dd;
        } else {
            unsigned u = *(const unsigned*)self;
            acc[0] = bf_lo(u) * dd; acc[1] = bf_hi(u) * dd;
        }
    }

    for (int base = 0; base < d; base += 64) {
        int e = base + lane;
        int s = 0; float nw = 0.0f;
        if (e < d) { s = csr_src[start + e]; nw = dis[s] * disd; }
        int cnt = min(64, d - base);
        for (int k = 0; k < cnt; k++) {
            int sk = __shfl(s, k);
            float nwk = __shfl(nw, k);
            const bf16* hr = ht + (size_t)sk * F + lane * VPL;
            if (VPL == 4) {
                uint2 u = *(const uint2*)hr;
                acc[0] += nwk * bf_lo(u.x); acc[1] += nwk * bf_hi(u.x);
                acc[2] += nwk * bf_lo(u.y); acc[3] += nwk * bf_hi(u.y);
            } else {
                unsigned u = *(const unsigned*)hr;
                acc[0] += nwk * bf_lo(u); acc[1] += nwk * bf_hi(u);
            }
        }
    }

    float* orow = out + (size_t)wid * F + lane * VPL;
#pragma unroll
    for (int c = 0; c < VPL; c++) {
        int f = lane * VPL + c;
        orow[c] = fmaxf(acc[c] * S[f] + T[f], 0.0f);
    }
}

// ---------------- graph pooling ----------------
__global__ void pool_k(const float* __restrict__ h, const int* __restrict__ batch,
                       float* __restrict__ psum, float* __restrict__ pmax,
                       int* __restrict__ pcnt, int n) {
    int w = (int)(((size_t)blockIdx.x * blockDim.x + threadIdx.x) >> 6);
    int lane = threadIdx.x & 63;
    if (w >= n) return;
    int g = batch[w];
    if (lane == 0) atomicAdd(&pcnt[g], 1);
    const float* hr = h + (size_t)w * 256;
#pragma unroll
    for (int c = 0; c < 4; c++) {
        int f = lane + 64 * c;
        float val = hr[f];
        atomicAdd(&psum[g * 256 + f], val);
        atomicMax((int*)&pmax[g * 256 + f], __float_as_int(val));  // val >= 0
    }
}

__global__ void build_z(const float* __restrict__ psum, const float* __restrict__ pmax,
                        const int* __restrict__ pcnt, float* __restrict__ z) {
    int i = blockIdx.x * blockDim.x + threadIdx.x;
    if (i >= NGRAPH * 256) return;
    int g = i >> 8, f = i & 255;
    float c = (float)max(pcnt[g], 1);
    z[g * 512 + f] = psum[i] / c;
    z[g * 512 + 256 + f] = pmax[i];
}

// ---------------- MLP GEMM (block per row) ----------------
template <int K, int NOUT, bool GELU>
__global__ void mlp_gemm(const float* __restrict__ A, const void* __restrict__ W,
                         const void* __restrict__ bias, float* __restrict__ C,
                         const int* __restrict__ flag) {
    __shared__ float a[K];
    int row = blockIdx.x;
    for (int idx = threadIdx.x; idx < K; idx += blockDim.x) a[idx] = A[row * K + idx];
    __syncthreads();
    int col = threadIdx.x;
    if (col < NOUT) {
        int isbf = *flag;
        float acc = load_f(bias, col, isbf);
        if (isbf) {
            const bf16* w = (const bf16*)W;
            for (int k = 0; k < K; k++) acc += a[k] * b2f(w[k * NOUT + col]);
        } else {
            const float* w = (const float*)W;
            for (int k = 0; k < K; k++) acc += a[k] * w[k * NOUT + col];
        }
        if (GELU) acc = 0.5f * acc * (1.0f + erff(acc * 0.70710678118654752f));
        C[row * NOUT + col] = acc;
    }
}

__global__ void write_out(const float* __restrict__ in, void* __restrict__ out,
                          int n, const int* __restrict__ flag) {
    int i = blockIdx.x * blockDim.x + threadIdx.x;
    if (i >= n) return;
    if (*flag) ((bf16*)out)[i] = __float2bfloat16(in[i]);
    else       ((float*)out)[i] = in[i];
}

extern "C" void kernel_launch(void* const* d_in, const int* in_sizes, int n_in,
                              void* d_out, int out_size, void* d_ws, size_t ws_size,
                              hipStream_t stream) {
    const void* x     = d_in[0];
    const int*  ei    = (const int*)d_in[1];
    const int*  batch = (const int*)d_in[2];
    const void *W1 = d_in[3],  *b1 = d_in[4],  *g1 = d_in[5],  *be1 = d_in[6],  *m1 = d_in[7],  *v1 = d_in[8];
    const void *W2 = d_in[9],  *b2 = d_in[10], *g2 = d_in[11], *be2 = d_in[12], *m2 = d_in[13], *v2 = d_in[14];
    const void *W3 = d_in[15], *b3 = d_in[16], *g3 = d_in[17], *be3 = d_in[18], *m3 = d_in[19], *v3 = d_in[20];
    const void *Wm1 = d_in[21], *bm1 = d_in[22];
    const void *Wm2 = d_in[23], *bm2 = d_in[24];
    const void *Wm3 = d_in[25], *bm3 = d_in[26];

    const int n = in_sizes[0] / 64;     // 50000
    const int E = in_sizes[1] / 2;      // 800000
    const int* src = ei;
    const int* dst = ei + E;

    // -------- workspace carving (256B aligned) --------
    size_t off = 0;
    auto carve = [&](size_t bytes) {
        void* p = (char*)d_ws + off;
        off += (bytes + 255) & ~(size_t)255;
        return p;
    };
    int*   flag  = (int*)carve(4);
    int*   total = (int*)carve(4);
    float* dis   = (float*)carve((size_t)n * 4);
    int*   deg_i = (int*)carve((size_t)n * 4);
    int*   rowst = (int*)carve((size_t)n * 4);
    int*   curs  = (int*)carve((size_t)n * 4);
    int*   csrc  = (int*)carve((size_t)E * 4);
    float* A     = (float*)carve((size_t)n * 256 * 4);   // fp32 h (post BN/ReLU)
    bf16*  B     = (bf16*)carve((size_t)n * 256 * 2);    // bf16 transformed feats
    float* W1f   = (float*)carve((size_t)64 * 128 * 4);
    float* W2f   = (float*)carve((size_t)128 * 256 * 4);
    float* W3f   = (float*)carve((size_t)256 * 256 * 4);
    float* S1 = (float*)carve(128 * 4); float* T1 = (float*)carve(128 * 4);
    float* S2 = (float*)carve(256 * 4); float* T2 = (float*)carve(256 * 4);
    float* S3 = (float*)carve(256 * 4); float* T3 = (float*)carve(256 * 4);
    float* psum = (float*)carve((size_t)NGRAPH * 256 * 4);
    float* pmax = (float*)carve((size_t)NGRAPH * 256 * 4);
    int*   pcnt = (int*)carve((size_t)NGRAPH * 4);
    float* z    = (float*)carve((size_t)NGRAPH * 512 * 4);
    float* z1   = (float*)carve((size_t)NGRAPH * 256 * 4);
    float* z2   = (float*)carve((size_t)NGRAPH * 128 * 4);
    float* z3   = (float*)carve((size_t)NGRAPH * 8 * 4);
    (void)ws_size; (void)n_in;

    const int BT = 256;

    // -------- dtype detection + weight converts + BN folding --------
    detect_dtype<<<1, 64, 0, stream>>>(x, flag);
    cvt<<<(64 * 128 + BT - 1) / BT, BT, 0, stream>>>(W1, W1f, 64 * 128, flag);
    cvt<<<(128 * 256 + BT - 1) / BT, BT, 0, stream>>>(W2, W2f, 128 * 256, flag);
    cvt<<<(256 * 256 + BT - 1) / BT, BT, 0, stream>>>(W3, W3f, 256 * 256, flag);
    fold_bn<<<1, 128, 0, stream>>>(b1, g1, be1, m1, v1, S1, T1, 128, flag);
    fold_bn<<<1, 256, 0, stream>>>(b2, g2, be2, m2, v2, S2, T2, 256, flag);
    fold_bn<<<1, 256, 0, stream>>>(b3, g3, be3, m3, v3, S3, T3, 256, flag);

    // -------- CSR build (once) --------
    hipMemsetAsync(deg_i, 0, (size_t)n * 4, stream);
    hipMemsetAsync(total, 0, 4, stream);
    count_deg_i<<<(E + BT - 1) / BT, BT, 0, stream>>>(dst, deg_i, E);
    reserve_rows<<<(n + BT - 1) / BT, BT, 0, stream>>>(deg_i, rowst, curs, dis, total, n);
    scatter_edges<<<(E + BT - 1) / BT, BT, 0, stream>>>(src, dst, curs, csrc, E);

    const int gemm_blocks = (n + 15) / 16;
    const int agg_blocks = (n * 64 + BT - 1) / BT;   // one wave per node

    // -------- layer 1: x(64) -> 128 --------
    gemm_node<64, 128, true><<<gemm_blocks, 128, 0, stream>>>(x, W1f, B, n, flag);
    csr_agg<2><<<agg_blocks, BT, 0, stream>>>(rowst, deg_i, dis, csrc, B, S1, T1, A, n);

    // -------- layer 2: 128 -> 256 --------
    gemm_node<128, 256, false><<<gemm_blocks, 256, 0, stream>>>(A, W2f, B, n, flag);
    csr_agg<4><<<agg_blocks, BT, 0, stream>>>(rowst, deg_i, dis, csrc, B, S2, T2, A, n);

    // -------- layer 3: 256 -> 256 --------
    gemm_node<256, 256, false><<<gemm_blocks, 256, 0, stream>>>(A, W3f, B, n, flag);
    csr_agg<4><<<agg_blocks, BT, 0, stream>>>(rowst, deg_i, dis, csrc, B, S3, T3, A, n);

    // -------- pooling --------
    hipMemsetAsync(psum, 0, (size_t)NGRAPH * 256 * 4, stream);
    hipMemsetAsync(pmax, 0, (size_t)NGRAPH * 256 * 4, stream);
    hipMemsetAsync(pcnt, 0, (size_t)NGRAPH * 4, stream);
    pool_k<<<(n * 64 + BT - 1) / BT, BT, 0, stream>>>(A, batch, psum, pmax, pcnt, n);
    build_z<<<(NGRAPH * 256 + BT - 1) / BT, BT, 0, stream>>>(psum, pmax, pcnt, z);

    // -------- MLP head --------
    mlp_gemm<512, 256, true><<<NGRAPH, 256, 0, stream>>>(z, Wm1, bm1, z1, flag);
    mlp_gemm<256, 128, true><<<NGRAPH, 256, 0, stream>>>(z1, Wm2, bm2, z2, flag);
    mlp_gemm<128, 6, false><<<NGRAPH, 128, 0, stream>>>(z2, Wm3, bm3, z3, flag);
    write_out<<<(NGRAPH * 6 + BT - 1) / BT, BT, 0, stream>>>(z3, d_out, NGRAPH * 6, flag);
}